// Round 8
// baseline (231.358 us; speedup 1.0000x reference)
//
#include <hip/hip_runtime.h>
#include <hip/hip_bf16.h>

#define D 512
#define NSEQ 2048
#define NB 8
#define QBLK 32
#define KVBLK 64
#define NTHREADS 512
#define NT (NSEQ / KVBLK)          // 32 kv tiles
#define ROWE 2056                  // subtiled layout: elems per 4-kv-row group
#define BUFE (16 * ROWE)           // 32896 elems = 65792 B per Bs buffer
#define SROWP (KVBLK + 4)          // f32 row for Ss
#define PROWP (KVBLK + 8)          // bf16 row for Ps

typedef __attribute__((ext_vector_type(8))) short bf16x8;
typedef __attribute__((ext_vector_type(4))) float f32x4;

static __device__ __forceinline__ unsigned short f2b(float f) {
  unsigned u = __builtin_bit_cast(unsigned, f);
  return (unsigned short)((u + 0x7FFFu + ((u >> 16) & 1u)) >> 16);
}

// ---------------- conv: fp32 B -> b16 [kv][d] (memory-bound, ~10us) ---------
__global__ __launch_bounds__(256) void conv_b16(const float* __restrict__ in,
                                                unsigned short* __restrict__ out) {
  size_t i = ((size_t)blockIdx.x * 256 + threadIdx.x) * 8;
  float4 v0 = *reinterpret_cast<const float4*>(in + i);
  float4 v1 = *reinterpret_cast<const float4*>(in + i + 4);
  bf16x8 h;
  h[0] = (short)f2b(v0.x); h[1] = (short)f2b(v0.y);
  h[2] = (short)f2b(v0.z); h[3] = (short)f2b(v0.w);
  h[4] = (short)f2b(v1.x); h[5] = (short)f2b(v1.y);
  h[6] = (short)f2b(v1.z); h[7] = (short)f2b(v1.w);
  *reinterpret_cast<bf16x8*>(out + i) = h;
}

// ---------------------------- v8 main kernel --------------------------------
// v7 post-mortem: occupancy fix worked (2 blocks/CU, 45%) but
// __launch_bounds__(512,4) -> VGPR cap 64 -> qf[16]+acc fully spilled
// (WRITE 114MB vs 33MB output; kernel became spill-BW-bound at ~880 GB/s).
// Empirical hipcc model (r4: (512,2)->128, r7: (512,4)->64): 2nd arg acts as
// min BLOCKS/CU (CUDA semantics). v8 = v7 with (512,2): cap 128 >= ~110 live
// regs -> no spills; LDS (79.9KB) still allows exactly 2 blocks/CU.
__global__ __launch_bounds__(NTHREADS, 2)
void attn_v8(const float* __restrict__ A, const unsigned short* __restrict__ B16,
             float* __restrict__ Out) {
  __shared__ __align__(16) unsigned short Bs[BUFE];
  __shared__ float Ss[QBLK * SROWP];
  __shared__ unsigned short Ps[QBLK * PROWP];
  __shared__ float mS[QBLK];
  __shared__ float lS[QBLK];
  __shared__ float aS[QBLK];

  const int tid  = threadIdx.x;
  const int wid  = tid >> 6;
  const int lane = tid & 63;
  const int l16  = lane & 15;
  const int g4   = lane >> 4;

  const int batch = blockIdx.x & 7;       // batch -> XCD (L2 locality for b panel)
  const int qt    = blockIdx.x >> 3;
  const int qbase = qt * QBLK;

  const float*          Ab   = A   + (size_t)batch * NSEQ * D;
  const unsigned short* Bb16 = B16 + (size_t)batch * NSEQ * D;
  float*                Ob   = Out + (size_t)batch * NSEQ * D;

  const float scale = 0.04419417382415922f;  // 1/sqrt(512)

  const int qi = wid >> 2;   // wave's q 16-tile for QK^T
  const int ki = wid & 3;    // wave's kv 16-tile for QK^T

  // ---- Q tile into registers (pre-scaled), 16 frags x 8 bf16 ----
  const float* Arow = Ab + (size_t)(qbase + qi * 16 + l16) * D;
  bf16x8 qf[16];
  #pragma unroll
  for (int ks = 0; ks < 16; ++ks) {
    int d0 = ks * 32 + g4 * 8;
    float4 v0 = *reinterpret_cast<const float4*>(Arow + d0);
    float4 v1 = *reinterpret_cast<const float4*>(Arow + d0 + 4);
    bf16x8 f;
    f[0] = (short)f2b(v0.x * scale); f[1] = (short)f2b(v0.y * scale);
    f[2] = (short)f2b(v0.z * scale); f[3] = (short)f2b(v0.w * scale);
    f[4] = (short)f2b(v1.x * scale); f[5] = (short)f2b(v1.y * scale);
    f[6] = (short)f2b(v1.z * scale); f[7] = (short)f2b(v1.w * scale);
    qf[ks] = f;
  }
  if (tid < QBLK) { mS[tid] = -1e30f; lS[tid] = 0.f; }

  f32x4 acc[2][4];
  #pragma unroll
  for (int mi = 0; mi < 2; ++mi)
    #pragma unroll
    for (int ni = 0; ni < 4; ++ni)
      acc[mi][ni] = (f32x4){0.f, 0.f, 0.f, 0.f};

  // ---- prologue: DMA tile 0 -> Bs, drain, barrier ----
  #pragma unroll
  for (int c = 0; c < 8; ++c) {
    int id = wid * 8 + c;
    int g = id >> 2, q = id & 3;
    const unsigned short* src = Bb16
        + (size_t)(g * 4 + ((lane >> 1) & 3)) * D
        + q * 128 + (lane >> 3) * 16 + (lane & 1) * 8;
    unsigned short* dst = &Bs[g * ROWE + q * 512];
    __builtin_amdgcn_global_load_lds(
        (const __attribute__((address_space(1))) void*)src,
        (__attribute__((address_space(3))) void*)dst, 16, 0, 0);
  }
  asm volatile("s_waitcnt vmcnt(0)" ::: "memory");
  asm volatile("s_waitcnt lgkmcnt(0)" ::: "memory");
  __builtin_amdgcn_s_barrier();

  for (int kt = 0; kt < NT; ++kt) {
    // ---- QK^T: wave (qi,ki), Q from regs, B via b128 from subtiled LDS ----
    {
      f32x4 s = {0.f, 0.f, 0.f, 0.f};
      const int bbase = (ki * 4 + (l16 >> 2)) * ROWE + (l16 & 3) * 16 + (g4 & 1) * 8;
      __builtin_amdgcn_s_setprio(1);
      #pragma unroll
      for (int ks = 0; ks < 16; ++ks) {
        const bf16x8 bf = *reinterpret_cast<const bf16x8*>(
            &Bs[bbase + (ks * 2 + (g4 >> 1)) * 64]);
        s = __builtin_amdgcn_mfma_f32_16x16x32_bf16(qf[ks], bf, s, 0, 0, 0);
      }
      __builtin_amdgcn_s_setprio(0);
      #pragma unroll
      for (int r = 0; r < 4; ++r)
        Ss[(qi * 16 + g4 * 4 + r) * SROWP + ki * 16 + l16] = s[r];
    }
    asm volatile("s_waitcnt lgkmcnt(0)" ::: "memory");
    __builtin_amdgcn_s_barrier();

    // ---- online softmax: wave w owns rows 4w..4w+3 ----
    {
      int row = wid * 4 + g4;
      float sv[4];
      float mloc = -1e30f;
      #pragma unroll
      for (int j = 0; j < 4; ++j) {
        sv[j] = Ss[row * SROWP + l16 + 16 * j];
        mloc = fmaxf(mloc, sv[j]);
      }
      #pragma unroll
      for (int off = 1; off < 16; off <<= 1)
        mloc = fmaxf(mloc, __shfl_xor(mloc, off));
      float mold = mS[row];
      float mnew = fmaxf(mold, mloc);
      float al = __expf(mold - mnew);
      float psum = 0.f;
      #pragma unroll
      for (int j = 0; j < 4; ++j) {
        float p = __expf(sv[j] - mnew);
        psum += p;
        Ps[row * PROWP + l16 + 16 * j] = f2b(p);
      }
      #pragma unroll
      for (int off = 1; off < 16; off <<= 1)
        psum += __shfl_xor(psum, off);
      if (l16 == 0) {
        mS[row] = mnew;
        lS[row] = lS[row] * al + psum;
        aS[row] = al;
      }
    }
    asm volatile("s_waitcnt lgkmcnt(0)" ::: "memory");
    __builtin_amdgcn_s_barrier();

    // ---- rescale acc + PV: wave owns d-slice [wid*64, +64) ----
    {
      float alv[2][4];
      #pragma unroll
      for (int mi = 0; mi < 2; ++mi)
        #pragma unroll
        for (int r = 0; r < 4; ++r)
          alv[mi][r] = aS[mi * 16 + g4 * 4 + r];
      #pragma unroll
      for (int mi = 0; mi < 2; ++mi)
        #pragma unroll
        for (int ni = 0; ni < 4; ++ni)
          #pragma unroll
          for (int r = 0; r < 4; ++r)
            acc[mi][ni][r] *= alv[mi][r];

      const unsigned short* Bc = &Bs[0];
      __builtin_amdgcn_s_setprio(1);
      #pragma unroll
      for (int ks = 0; ks < 2; ++ks) {
        bf16x8 pf[2];
        #pragma unroll
        for (int mi = 0; mi < 2; ++mi)
          pf[mi] = *reinterpret_cast<const bf16x8*>(
              &Ps[(mi * 16 + l16) * PROWP + ks * 32 + g4 * 8]);
        #pragma unroll
        for (int ni = 0; ni < 4; ++ni) {
          bf16x8 vv;
          #pragma unroll
          for (int j = 0; j < 8; ++j)
            vv[j] = (short)Bc[(ks * 8 + g4 * 2 + (j >> 2)) * ROWE
                              + (wid * 4 + ni) * 64 + (j & 3) * 16 + l16];
          #pragma unroll
          for (int mi = 0; mi < 2; ++mi)
            acc[mi][ni] = __builtin_amdgcn_mfma_f32_16x16x32_bf16(pf[mi], vv, acc[mi][ni], 0, 0, 0);
        }
      }
      __builtin_amdgcn_s_setprio(0);
    }

    // ---- all PV reads of Bs done across the block -> safe to overwrite ----
    __builtin_amdgcn_s_barrier();
    if (kt + 1 < NT) {
      const unsigned short* Bt = Bb16 + (size_t)(kt + 1) * KVBLK * D;
      #pragma unroll
      for (int c = 0; c < 8; ++c) {
        int id = wid * 8 + c;
        int g = id >> 2, q = id & 3;
        const unsigned short* src = Bt
            + (size_t)(g * 4 + ((lane >> 1) & 3)) * D
            + q * 128 + (lane >> 3) * 16 + (lane & 1) * 8;
        unsigned short* dst = &Bs[g * ROWE + q * 512];
        __builtin_amdgcn_global_load_lds(
            (const __attribute__((address_space(1))) void*)src,
            (__attribute__((address_space(3))) void*)dst, 16, 0, 0);
      }
      asm volatile("s_waitcnt vmcnt(0)" ::: "memory");
    }
    __builtin_amdgcn_s_barrier();     // Bs(kt+1) ready for all waves
  }

  // ---- epilogue: out = acc / l + a ----
  float rl[2][4];
  #pragma unroll
  for (int mi = 0; mi < 2; ++mi)
    #pragma unroll
    for (int r = 0; r < 4; ++r)
      rl[mi][r] = 1.0f / lS[mi * 16 + g4 * 4 + r];
  #pragma unroll
  for (int mi = 0; mi < 2; ++mi)
    #pragma unroll
    for (int ni = 0; ni < 4; ++ni)
      #pragma unroll
      for (int r = 0; r < 4; ++r) {
        int q = qbase + mi * 16 + g4 * 4 + r;
        int d = wid * 64 + ni * 16 + l16;
        size_t off = (size_t)q * D + d;
        Ob[off] = acc[mi][ni][r] * rl[mi][r] + Ab[off];
      }
}

// ---------- fallback: in-kernel convert staging (no workspace) --------------
__global__ __launch_bounds__(NTHREADS, 2)
void attn_fb(const float* __restrict__ A, const float* __restrict__ B32,
             float* __restrict__ Out) {
  __shared__ __align__(16) unsigned short Bs[BUFE];
  __shared__ float Ss[QBLK * SROWP];
  __shared__ unsigned short Ps[QBLK * PROWP];
  __shared__ float mS[QBLK];
  __shared__ float lS[QBLK];
  __shared__ float aS[QBLK];

  const int tid  = threadIdx.x;
  const int wid  = tid >> 6;
  const int lane = tid & 63;
  const int l16  = lane & 15;
  const int g4   = lane >> 4;

  const int batch = blockIdx.x & 7;
  const int qt    = blockIdx.x >> 3;
  const int qbase = qt * QBLK;

  const float* Ab   = A   + (size_t)batch * NSEQ * D;
  const float* Bb32 = B32 + (size_t)batch * NSEQ * D;
  float*       Ob   = Out + (size_t)batch * NSEQ * D;

  const float scale = 0.04419417382415922f;

  const int qi = wid >> 2;
  const int ki = wid & 3;

  const float* Arow = Ab + (size_t)(qbase + qi * 16 + l16) * D;
  bf16x8 qf[16];
  #pragma unroll
  for (int ks = 0; ks < 16; ++ks) {
    int d0 = ks * 32 + g4 * 8;
    float4 v0 = *reinterpret_cast<const float4*>(Arow + d0);
    float4 v1 = *reinterpret_cast<const float4*>(Arow + d0 + 4);
    bf16x8 f;
    f[0] = (short)f2b(v0.x * scale); f[1] = (short)f2b(v0.y * scale);
    f[2] = (short)f2b(v0.z * scale); f[3] = (short)f2b(v0.w * scale);
    f[4] = (short)f2b(v1.x * scale); f[5] = (short)f2b(v1.y * scale);
    f[6] = (short)f2b(v1.z * scale); f[7] = (short)f2b(v1.w * scale);
    qf[ks] = f;
  }
  if (tid < QBLK) { mS[tid] = -1e30f; lS[tid] = 0.f; }

  f32x4 acc[2][4];
  #pragma unroll
  for (int mi = 0; mi < 2; ++mi)
    #pragma unroll
    for (int ni = 0; ni < 4; ++ni)
      acc[mi][ni] = (f32x4){0.f, 0.f, 0.f, 0.f};

  for (int kt = 0; kt < NT; ++kt) {
    __builtin_amdgcn_s_barrier();
    const float* Bt = Bb32 + (size_t)kt * KVBLK * D;
    #pragma unroll
    for (int c = 0; c < 8; ++c) {
      int id = wid * 8 + c;
      int g = id >> 2, q = id & 3;
      int kv = g * 4 + ((lane >> 1) & 3);
      int d  = q * 128 + (lane >> 3) * 16 + (lane & 1) * 8;
      const float* s = Bt + (size_t)kv * D + d;
      float4 v0 = *reinterpret_cast<const float4*>(s);
      float4 v1 = *reinterpret_cast<const float4*>(s + 4);
      bf16x8 h;
      h[0] = (short)f2b(v0.x); h[1] = (short)f2b(v0.y);
      h[2] = (short)f2b(v0.z); h[3] = (short)f2b(v0.w);
      h[4] = (short)f2b(v1.x); h[5] = (short)f2b(v1.y);
      h[6] = (short)f2b(v1.z); h[7] = (short)f2b(v1.w);
      *reinterpret_cast<bf16x8*>(&Bs[g * ROWE + q * 512 + lane * 8]) = h;
    }
    asm volatile("s_waitcnt lgkmcnt(0)" ::: "memory");
    __builtin_amdgcn_s_barrier();

    {
      f32x4 s = {0.f, 0.f, 0.f, 0.f};
      const int bbase = (ki * 4 + (l16 >> 2)) * ROWE + (l16 & 3) * 16 + (g4 & 1) * 8;
      #pragma unroll
      for (int ks = 0; ks < 16; ++ks) {
        const bf16x8 bf = *reinterpret_cast<const bf16x8*>(
            &Bs[bbase + (ks * 2 + (g4 >> 1)) * 64]);
        s = __builtin_amdgcn_mfma_f32_16x16x32_bf16(qf[ks], bf, s, 0, 0, 0);
      }
      #pragma unroll
      for (int r = 0; r < 4; ++r)
        Ss[(qi * 16 + g4 * 4 + r) * SROWP + ki * 16 + l16] = s[r];
    }
    asm volatile("s_waitcnt lgkmcnt(0)" ::: "memory");
    __builtin_amdgcn_s_barrier();

    {
      int row = wid * 4 + g4;
      float sv[4];
      float mloc = -1e30f;
      #pragma unroll
      for (int j = 0; j < 4; ++j) {
        sv[j] = Ss[row * SROWP + l16 + 16 * j];
        mloc = fmaxf(mloc, sv[j]);
      }
      #pragma unroll
      for (int off = 1; off < 16; off <<= 1)
        mloc = fmaxf(mloc, __shfl_xor(mloc, off));
      float mold = mS[row];
      float mnew = fmaxf(mold, mloc);
      float al = __expf(mold - mnew);
      float psum = 0.f;
      #pragma unroll
      for (int j = 0; j < 4; ++j) {
        float p = __expf(sv[j] - mnew);
        psum += p;
        Ps[row * PROWP + l16 + 16 * j] = f2b(p);
      }
      #pragma unroll
      for (int off = 1; off < 16; off <<= 1)
        psum += __shfl_xor(psum, off);
      if (l16 == 0) {
        mS[row] = mnew;
        lS[row] = lS[row] * al + psum;
        aS[row] = al;
      }
    }
    asm volatile("s_waitcnt lgkmcnt(0)" ::: "memory");
    __builtin_amdgcn_s_barrier();

    {
      float alv[2][4];
      #pragma unroll
      for (int mi = 0; mi < 2; ++mi)
        #pragma unroll
        for (int r = 0; r < 4; ++r)
          alv[mi][r] = aS[mi * 16 + g4 * 4 + r];
      #pragma unroll
      for (int mi = 0; mi < 2; ++mi)
        #pragma unroll
        for (int ni = 0; ni < 4; ++ni)
          #pragma unroll
          for (int r = 0; r < 4; ++r)
            acc[mi][ni][r] *= alv[mi][r];

      #pragma unroll
      for (int ks = 0; ks < 2; ++ks) {
        bf16x8 pf[2];
        #pragma unroll
        for (int mi = 0; mi < 2; ++mi)
          pf[mi] = *reinterpret_cast<const bf16x8*>(
              &Ps[(mi * 16 + l16) * PROWP + ks * 32 + g4 * 8]);
        #pragma unroll
        for (int ni = 0; ni < 4; ++ni) {
          bf16x8 vv;
          #pragma unroll
          for (int j = 0; j < 8; ++j)
            vv[j] = (short)Bs[(ks * 8 + g4 * 2 + (j >> 2)) * ROWE
                              + (wid * 4 + ni) * 64 + (j & 3) * 16 + l16];
          #pragma unroll
          for (int mi = 0; mi < 2; ++mi)
            acc[mi][ni] = __builtin_amdgcn_mfma_f32_16x16x32_bf16(pf[mi], vv, acc[mi][ni], 0, 0, 0);
        }
      }
    }
  }

  float rl[2][4];
  #pragma unroll
  for (int mi = 0; mi < 2; ++mi)
    #pragma unroll
    for (int r = 0; r < 4; ++r)
      rl[mi][r] = 1.0f / lS[mi * 16 + g4 * 4 + r];
  #pragma unroll
  for (int mi = 0; mi < 2; ++mi)
    #pragma unroll
    for (int ni = 0; ni < 4; ++ni)
      #pragma unroll
      for (int r = 0; r < 4; ++r) {
        int q = qbase + mi * 16 + g4 * 4 + r;
        int d = wid * 64 + ni * 16 + l16;
        size_t off = (size_t)q * D + d;
        Ob[off] = acc[mi][ni][r] * rl[mi][r] + Ab[off];
      }
}

extern "C" void kernel_launch(void* const* d_in, const int* in_sizes, int n_in,
                              void* d_out, int out_size, void* d_ws, size_t ws_size,
                              hipStream_t stream) {
  const float* a = (const float*)d_in[0];
  const float* b = (const float*)d_in[1];
  float* out = (float*)d_out;
  const size_t need = (size_t)NB * NSEQ * D * sizeof(unsigned short);  // 16 MB
  dim3 grid(NB * (NSEQ / QBLK));
  dim3 block(NTHREADS);
  if (ws_size >= need) {
    unsigned short* b16 = (unsigned short*)d_ws;
    conv_b16<<<4096, 256, 0, stream>>>(b, b16);
    attn_v8<<<grid, block, 0, stream>>>(a, b16, out);
  } else {
    attn_fb<<<grid, block, 0, stream>>>(a, b, out);
  }
}

// Round 9
// 227.523 us; speedup vs baseline: 1.0169x; 1.0169x over previous
//
#include <hip/hip_runtime.h>
#include <hip/hip_bf16.h>

#define D 512
#define NSEQ 2048
#define NB 8
#define QBLK 32
#define KVBLK 64
#define NTHREADS 512
#define NT (NSEQ / KVBLK)          // 32 kv tiles
#define ROWE 2056                  // subtiled layout: elems per 4-kv-row group
#define BUFE (16 * ROWE)           // 32896 elems = 65792 B per Bs buffer
#define SROWP (KVBLK + 4)          // f32 row for Ss
#define PROWP (KVBLK + 8)          // bf16 row for Ps

typedef __attribute__((ext_vector_type(8))) short bf16x8;
typedef __attribute__((ext_vector_type(4))) float f32x4;

#if __has_attribute(amdgpu_num_vgpr)
#define ARCH_VGPR_CAP __attribute__((amdgpu_num_vgpr(96)))
#else
#define ARCH_VGPR_CAP
#endif

static __device__ __forceinline__ unsigned short f2b(float f) {
  unsigned u = __builtin_bit_cast(unsigned, f);
  return (unsigned short)((u + 0x7FFFu + ((u >> 16) & 1u)) >> 16);
}

// ---------------- conv: fp32 B -> b16 [kv][d] (memory-bound, ~10us) ---------
__global__ __launch_bounds__(256) void conv_b16(const float* __restrict__ in,
                                                unsigned short* __restrict__ out) {
  size_t i = ((size_t)blockIdx.x * 256 + threadIdx.x) * 8;
  float4 v0 = *reinterpret_cast<const float4*>(in + i);
  float4 v1 = *reinterpret_cast<const float4*>(in + i + 4);
  bf16x8 h;
  h[0] = (short)f2b(v0.x); h[1] = (short)f2b(v0.y);
  h[2] = (short)f2b(v0.z); h[3] = (short)f2b(v0.w);
  h[4] = (short)f2b(v1.x); h[5] = (short)f2b(v1.y);
  h[6] = (short)f2b(v1.z); h[7] = (short)f2b(v1.w);
  *reinterpret_cast<bf16x8*>(out + i) = h;
}

// ---------------------------- v9 main kernel --------------------------------
// r8 post-mortem: VGPR_Count=100 is ARCH only; +32 AGPR acc = 132-136 unified
// > 128 -> 3 waves/SIMD -> an 8-wave block can't pair -> 1 block/CU (23%).
// v9: cap arch VGPRs at 96 (96+32 AGPR = 128 = exactly 4 waves/SIMD) so two
// 79.9KB-LDS blocks co-reside (159.7 <= 160KB). Sibling block, phase-shifted,
// fills the lockstep stalls (r7 showed 45% occ even paid for 3.5x spill
// traffic at no net loss). Everything else identical to v8.
__global__ __launch_bounds__(NTHREADS, 2) ARCH_VGPR_CAP
void attn_v9(const float* __restrict__ A, const unsigned short* __restrict__ B16,
             float* __restrict__ Out) {
  __shared__ __align__(16) unsigned short Bs[BUFE];
  __shared__ float Ss[QBLK * SROWP];
  __shared__ unsigned short Ps[QBLK * PROWP];
  __shared__ float mS[QBLK];
  __shared__ float lS[QBLK];
  __shared__ float aS[QBLK];

  const int tid  = threadIdx.x;
  const int wid  = tid >> 6;
  const int lane = tid & 63;
  const int l16  = lane & 15;
  const int g4   = lane >> 4;

  const int batch = blockIdx.x & 7;       // batch -> XCD (L2 locality for b panel)
  const int qt    = blockIdx.x >> 3;
  const int qbase = qt * QBLK;

  const float*          Ab   = A   + (size_t)batch * NSEQ * D;
  const unsigned short* Bb16 = B16 + (size_t)batch * NSEQ * D;
  float*                Ob   = Out + (size_t)batch * NSEQ * D;

  const float scale = 0.04419417382415922f;  // 1/sqrt(512)

  const int qi = wid >> 2;   // wave's q 16-tile for QK^T
  const int ki = wid & 3;    // wave's kv 16-tile for QK^T

  // ---- Q tile into registers (pre-scaled), 16 frags x 8 bf16 ----
  const float* Arow = Ab + (size_t)(qbase + qi * 16 + l16) * D;
  bf16x8 qf[16];
  #pragma unroll
  for (int ks = 0; ks < 16; ++ks) {
    int d0 = ks * 32 + g4 * 8;
    float4 v0 = *reinterpret_cast<const float4*>(Arow + d0);
    float4 v1 = *reinterpret_cast<const float4*>(Arow + d0 + 4);
    bf16x8 f;
    f[0] = (short)f2b(v0.x * scale); f[1] = (short)f2b(v0.y * scale);
    f[2] = (short)f2b(v0.z * scale); f[3] = (short)f2b(v0.w * scale);
    f[4] = (short)f2b(v1.x * scale); f[5] = (short)f2b(v1.y * scale);
    f[6] = (short)f2b(v1.z * scale); f[7] = (short)f2b(v1.w * scale);
    qf[ks] = f;
  }
  if (tid < QBLK) { mS[tid] = -1e30f; lS[tid] = 0.f; }

  f32x4 acc[2][4];
  #pragma unroll
  for (int mi = 0; mi < 2; ++mi)
    #pragma unroll
    for (int ni = 0; ni < 4; ++ni)
      acc[mi][ni] = (f32x4){0.f, 0.f, 0.f, 0.f};

  // ---- prologue: DMA tile 0 -> Bs, drain, barrier ----
  #pragma unroll
  for (int c = 0; c < 8; ++c) {
    int id = wid * 8 + c;
    int g = id >> 2, q = id & 3;
    const unsigned short* src = Bb16
        + (size_t)(g * 4 + ((lane >> 1) & 3)) * D
        + q * 128 + (lane >> 3) * 16 + (lane & 1) * 8;
    unsigned short* dst = &Bs[g * ROWE + q * 512];
    __builtin_amdgcn_global_load_lds(
        (const __attribute__((address_space(1))) void*)src,
        (__attribute__((address_space(3))) void*)dst, 16, 0, 0);
  }
  asm volatile("s_waitcnt vmcnt(0)" ::: "memory");
  asm volatile("s_waitcnt lgkmcnt(0)" ::: "memory");
  __builtin_amdgcn_s_barrier();

  for (int kt = 0; kt < NT; ++kt) {
    // ---- QK^T: wave (qi,ki), Q from regs, B via b128 from subtiled LDS ----
    {
      f32x4 s = {0.f, 0.f, 0.f, 0.f};
      const int bbase = (ki * 4 + (l16 >> 2)) * ROWE + (l16 & 3) * 16 + (g4 & 1) * 8;
      __builtin_amdgcn_s_setprio(1);
      #pragma unroll
      for (int ks = 0; ks < 16; ++ks) {
        const bf16x8 bf = *reinterpret_cast<const bf16x8*>(
            &Bs[bbase + (ks * 2 + (g4 >> 1)) * 64]);
        s = __builtin_amdgcn_mfma_f32_16x16x32_bf16(qf[ks], bf, s, 0, 0, 0);
      }
      __builtin_amdgcn_s_setprio(0);
      #pragma unroll
      for (int r = 0; r < 4; ++r)
        Ss[(qi * 16 + g4 * 4 + r) * SROWP + ki * 16 + l16] = s[r];
    }
    asm volatile("s_waitcnt lgkmcnt(0)" ::: "memory");
    __builtin_amdgcn_s_barrier();

    // ---- online softmax: wave w owns rows 4w..4w+3 ----
    {
      int row = wid * 4 + g4;
      float sv[4];
      float mloc = -1e30f;
      #pragma unroll
      for (int j = 0; j < 4; ++j) {
        sv[j] = Ss[row * SROWP + l16 + 16 * j];
        mloc = fmaxf(mloc, sv[j]);
      }
      #pragma unroll
      for (int off = 1; off < 16; off <<= 1)
        mloc = fmaxf(mloc, __shfl_xor(mloc, off));
      float mold = mS[row];
      float mnew = fmaxf(mold, mloc);
      float al = __expf(mold - mnew);
      float psum = 0.f;
      #pragma unroll
      for (int j = 0; j < 4; ++j) {
        float p = __expf(sv[j] - mnew);
        psum += p;
        Ps[row * PROWP + l16 + 16 * j] = f2b(p);
      }
      #pragma unroll
      for (int off = 1; off < 16; off <<= 1)
        psum += __shfl_xor(psum, off);
      if (l16 == 0) {
        mS[row] = mnew;
        lS[row] = lS[row] * al + psum;
        aS[row] = al;
      }
    }
    asm volatile("s_waitcnt lgkmcnt(0)" ::: "memory");
    __builtin_amdgcn_s_barrier();

    // ---- rescale acc (1 live temp) + PV: wave owns d-slice [wid*64,+64) ----
    {
      #pragma unroll
      for (int mi = 0; mi < 2; ++mi)
        #pragma unroll
        for (int r = 0; r < 4; ++r) {
          float a = aS[mi * 16 + g4 * 4 + r];
          #pragma unroll
          for (int ni = 0; ni < 4; ++ni)
            acc[mi][ni][r] *= a;
        }

      const unsigned short* Bc = &Bs[0];
      __builtin_amdgcn_s_setprio(1);
      #pragma unroll
      for (int ks = 0; ks < 2; ++ks) {
        bf16x8 pf[2];
        #pragma unroll
        for (int mi = 0; mi < 2; ++mi)
          pf[mi] = *reinterpret_cast<const bf16x8*>(
              &Ps[(mi * 16 + l16) * PROWP + ks * 32 + g4 * 8]);
        #pragma unroll
        for (int ni = 0; ni < 4; ++ni) {
          bf16x8 vv;
          #pragma unroll
          for (int j = 0; j < 8; ++j)
            vv[j] = (short)Bc[(ks * 8 + g4 * 2 + (j >> 2)) * ROWE
                              + (wid * 4 + ni) * 64 + (j & 3) * 16 + l16];
          #pragma unroll
          for (int mi = 0; mi < 2; ++mi)
            acc[mi][ni] = __builtin_amdgcn_mfma_f32_16x16x32_bf16(pf[mi], vv, acc[mi][ni], 0, 0, 0);
        }
      }
      __builtin_amdgcn_s_setprio(0);
    }

    // ---- all PV reads of Bs done across the block -> safe to overwrite ----
    __builtin_amdgcn_s_barrier();
    if (kt + 1 < NT) {
      const unsigned short* Bt = Bb16 + (size_t)(kt + 1) * KVBLK * D;
      #pragma unroll
      for (int c = 0; c < 8; ++c) {
        int id = wid * 8 + c;
        int g = id >> 2, q = id & 3;
        const unsigned short* src = Bt
            + (size_t)(g * 4 + ((lane >> 1) & 3)) * D
            + q * 128 + (lane >> 3) * 16 + (lane & 1) * 8;
        unsigned short* dst = &Bs[g * ROWE + q * 512];
        __builtin_amdgcn_global_load_lds(
            (const __attribute__((address_space(1))) void*)src,
            (__attribute__((address_space(3))) void*)dst, 16, 0, 0);
      }
      asm volatile("s_waitcnt vmcnt(0)" ::: "memory");
    }
    __builtin_amdgcn_s_barrier();     // Bs(kt+1) ready for all waves
  }

  // ---- epilogue: out = acc / l + a ----
  #pragma unroll
  for (int mi = 0; mi < 2; ++mi)
    #pragma unroll
    for (int r = 0; r < 4; ++r) {
      float rl = 1.0f / lS[mi * 16 + g4 * 4 + r];
      #pragma unroll
      for (int ni = 0; ni < 4; ++ni) {
        int q = qbase + mi * 16 + g4 * 4 + r;
        int d = wid * 64 + ni * 16 + l16;
        size_t off = (size_t)q * D + d;
        Ob[off] = acc[mi][ni][r] * rl + Ab[off];
      }
    }
}

// ---------- fallback: in-kernel convert staging (no workspace) --------------
__global__ __launch_bounds__(NTHREADS, 2)
void attn_fb(const float* __restrict__ A, const float* __restrict__ B32,
             float* __restrict__ Out) {
  __shared__ __align__(16) unsigned short Bs[BUFE];
  __shared__ float Ss[QBLK * SROWP];
  __shared__ unsigned short Ps[QBLK * PROWP];
  __shared__ float mS[QBLK];
  __shared__ float lS[QBLK];
  __shared__ float aS[QBLK];

  const int tid  = threadIdx.x;
  const int wid  = tid >> 6;
  const int lane = tid & 63;
  const int l16  = lane & 15;
  const int g4   = lane >> 4;

  const int batch = blockIdx.x & 7;
  const int qt    = blockIdx.x >> 3;
  const int qbase = qt * QBLK;

  const float* Ab   = A   + (size_t)batch * NSEQ * D;
  const float* Bb32 = B32 + (size_t)batch * NSEQ * D;
  float*       Ob   = Out + (size_t)batch * NSEQ * D;

  const float scale = 0.04419417382415922f;

  const int qi = wid >> 2;
  const int ki = wid & 3;

  const float* Arow = Ab + (size_t)(qbase + qi * 16 + l16) * D;
  bf16x8 qf[16];
  #pragma unroll
  for (int ks = 0; ks < 16; ++ks) {
    int d0 = ks * 32 + g4 * 8;
    float4 v0 = *reinterpret_cast<const float4*>(Arow + d0);
    float4 v1 = *reinterpret_cast<const float4*>(Arow + d0 + 4);
    bf16x8 f;
    f[0] = (short)f2b(v0.x * scale); f[1] = (short)f2b(v0.y * scale);
    f[2] = (short)f2b(v0.z * scale); f[3] = (short)f2b(v0.w * scale);
    f[4] = (short)f2b(v1.x * scale); f[5] = (short)f2b(v1.y * scale);
    f[6] = (short)f2b(v1.z * scale); f[7] = (short)f2b(v1.w * scale);
    qf[ks] = f;
  }
  if (tid < QBLK) { mS[tid] = -1e30f; lS[tid] = 0.f; }

  f32x4 acc[2][4];
  #pragma unroll
  for (int mi = 0; mi < 2; ++mi)
    #pragma unroll
    for (int ni = 0; ni < 4; ++ni)
      acc[mi][ni] = (f32x4){0.f, 0.f, 0.f, 0.f};

  for (int kt = 0; kt < NT; ++kt) {
    __builtin_amdgcn_s_barrier();
    const float* Bt = Bb32 + (size_t)kt * KVBLK * D;
    #pragma unroll
    for (int c = 0; c < 8; ++c) {
      int id = wid * 8 + c;
      int g = id >> 2, q = id & 3;
      int kv = g * 4 + ((lane >> 1) & 3);
      int d  = q * 128 + (lane >> 3) * 16 + (lane & 1) * 8;
      const float* s = Bt + (size_t)kv * D + d;
      float4 v0 = *reinterpret_cast<const float4*>(s);
      float4 v1 = *reinterpret_cast<const float4*>(s + 4);
      bf16x8 h;
      h[0] = (short)f2b(v0.x); h[1] = (short)f2b(v0.y);
      h[2] = (short)f2b(v0.z); h[3] = (short)f2b(v0.w);
      h[4] = (short)f2b(v1.x); h[5] = (short)f2b(v1.y);
      h[6] = (short)f2b(v1.z); h[7] = (short)f2b(v1.w);
      *reinterpret_cast<bf16x8*>(&Bs[g * ROWE + q * 512 + lane * 8]) = h;
    }
    asm volatile("s_waitcnt lgkmcnt(0)" ::: "memory");
    __builtin_amdgcn_s_barrier();

    {
      f32x4 s = {0.f, 0.f, 0.f, 0.f};
      const int bbase = (ki * 4 + (l16 >> 2)) * ROWE + (l16 & 3) * 16 + (g4 & 1) * 8;
      #pragma unroll
      for (int ks = 0; ks < 16; ++ks) {
        const bf16x8 bf = *reinterpret_cast<const bf16x8*>(
            &Bs[bbase + (ks * 2 + (g4 >> 1)) * 64]);
        s = __builtin_amdgcn_mfma_f32_16x16x32_bf16(qf[ks], bf, s, 0, 0, 0);
      }
      #pragma unroll
      for (int r = 0; r < 4; ++r)
        Ss[(qi * 16 + g4 * 4 + r) * SROWP + ki * 16 + l16] = s[r];
    }
    asm volatile("s_waitcnt lgkmcnt(0)" ::: "memory");
    __builtin_amdgcn_s_barrier();

    {
      int row = wid * 4 + g4;
      float sv[4];
      float mloc = -1e30f;
      #pragma unroll
      for (int j = 0; j < 4; ++j) {
        sv[j] = Ss[row * SROWP + l16 + 16 * j];
        mloc = fmaxf(mloc, sv[j]);
      }
      #pragma unroll
      for (int off = 1; off < 16; off <<= 1)
        mloc = fmaxf(mloc, __shfl_xor(mloc, off));
      float mold = mS[row];
      float mnew = fmaxf(mold, mloc);
      float al = __expf(mold - mnew);
      float psum = 0.f;
      #pragma unroll
      for (int j = 0; j < 4; ++j) {
        float p = __expf(sv[j] - mnew);
        psum += p;
        Ps[row * PROWP + l16 + 16 * j] = f2b(p);
      }
      #pragma unroll
      for (int off = 1; off < 16; off <<= 1)
        psum += __shfl_xor(psum, off);
      if (l16 == 0) {
        mS[row] = mnew;
        lS[row] = lS[row] * al + psum;
        aS[row] = al;
      }
    }
    asm volatile("s_waitcnt lgkmcnt(0)" ::: "memory");
    __builtin_amdgcn_s_barrier();

    {
      #pragma unroll
      for (int mi = 0; mi < 2; ++mi)
        #pragma unroll
        for (int r = 0; r < 4; ++r) {
          float a = aS[mi * 16 + g4 * 4 + r];
          #pragma unroll
          for (int ni = 0; ni < 4; ++ni)
            acc[mi][ni][r] *= a;
        }

      #pragma unroll
      for (int ks = 0; ks < 2; ++ks) {
        bf16x8 pf[2];
        #pragma unroll
        for (int mi = 0; mi < 2; ++mi)
          pf[mi] = *reinterpret_cast<const bf16x8*>(
              &Ps[(mi * 16 + l16) * PROWP + ks * 32 + g4 * 8]);
        #pragma unroll
        for (int ni = 0; ni < 4; ++ni) {
          bf16x8 vv;
          #pragma unroll
          for (int j = 0; j < 8; ++j)
            vv[j] = (short)Bs[(ks * 8 + g4 * 2 + (j >> 2)) * ROWE
                              + (wid * 4 + ni) * 64 + (j & 3) * 16 + l16];
          #pragma unroll
          for (int mi = 0; mi < 2; ++mi)
            acc[mi][ni] = __builtin_amdgcn_mfma_f32_16x16x32_bf16(pf[mi], vv, acc[mi][ni], 0, 0, 0);
        }
      }
    }
  }

  #pragma unroll
  for (int mi = 0; mi < 2; ++mi)
    #pragma unroll
    for (int r = 0; r < 4; ++r) {
      float rl = 1.0f / lS[mi * 16 + g4 * 4 + r];
      #pragma unroll
      for (int ni = 0; ni < 4; ++ni) {
        int q = qbase + mi * 16 + g4 * 4 + r;
        int d = wid * 64 + ni * 16 + l16;
        size_t off = (size_t)q * D + d;
        Ob[off] = acc[mi][ni][r] * rl + Ab[off];
      }
    }
}

extern "C" void kernel_launch(void* const* d_in, const int* in_sizes, int n_in,
                              void* d_out, int out_size, void* d_ws, size_t ws_size,
                              hipStream_t stream) {
  const float* a = (const float*)d_in[0];
  const float* b = (const float*)d_in[1];
  float* out = (float*)d_out;
  const size_t need = (size_t)NB * NSEQ * D * sizeof(unsigned short);  // 16 MB
  dim3 grid(NB * (NSEQ / QBLK));
  dim3 block(NTHREADS);
  if (ws_size >= need) {
    unsigned short* b16 = (unsigned short*)d_ws;
    conv_b16<<<4096, 256, 0, stream>>>(b, b16);
    attn_v9<<<grid, block, 0, stream>>>(a, b16, out);
  } else {
    attn_fb<<<grid, block, 0, stream>>>(a, b, out);
  }
}

// Round 10
// 163.885 us; speedup vs baseline: 1.4117x; 1.3883x over previous
//
#include <hip/hip_runtime.h>
#include <hip/hip_bf16.h>

#define D 512
#define NSEQ 2048
#define NB 8
#define QBLK 64
#define KVBLK 64
#define NTHREADS 512
#define NT (NSEQ / KVBLK)          // 32 kv tiles
#define ROWE 2056                  // subtiled layout: elems per 4-row group (4096B + 16B pad)
#define BUFE (16 * ROWE)           // 65792 B per [64][512] bf16 buffer
#define SROWP 68                   // f32 row stride for Ss (16B-align for float4)
#define PROWP 72                   // bf16 row stride for Ps (16B-align for bf16x8)

typedef __attribute__((ext_vector_type(8))) short bf16x8;
typedef __attribute__((ext_vector_type(4))) float f32x4;

static __device__ __forceinline__ unsigned short f2b(float f) {
  unsigned u = __builtin_bit_cast(unsigned, f);
  return (unsigned short)((u + 0x7FFFu + ((u >> 16) & 1u)) >> 16);
}

// ---------------- conv: fp32 B -> b16 [kv][d] (memory-bound, ~10us) ---------
__global__ __launch_bounds__(256) void conv_b16(const float* __restrict__ in,
                                                unsigned short* __restrict__ out) {
  size_t i = ((size_t)blockIdx.x * 256 + threadIdx.x) * 8;
  float4 v0 = *reinterpret_cast<const float4*>(in + i);
  float4 v1 = *reinterpret_cast<const float4*>(in + i + 4);
  bf16x8 h;
  h[0] = (short)f2b(v0.x); h[1] = (short)f2b(v0.y);
  h[2] = (short)f2b(v0.z); h[3] = (short)f2b(v0.w);
  h[4] = (short)f2b(v1.x); h[5] = (short)f2b(v1.y);
  h[6] = (short)f2b(v1.z); h[7] = (short)f2b(v1.w);
  *reinterpret_cast<bf16x8*>(out + i) = h;
}

// ---------------------------- v10 main kernel -------------------------------
// r9 post-mortem: structure is LDS-PIPE-THROUGHPUT bound (~5.6K LDS-cy/tile vs
// 6.8K measured; co-resident blocks share the pipe -> occupancy chase was the
// wrong lever). v10: QBLK 64 -> grid 256 = ONE block/CU (kills the 2x
// sequential block-wave) and 2x FLOP per staged tile (LDS-cy/FLOP -40%).
// Q in LDS (v6-proven subtile addressing); acc[4][4] = 64 AGPR fits the
// 256-reg/wave budget at 2 waves/SIMD. v9's 4-barrier full-drain skeleton.
// LDS: Bs 65792 + Qs 65792 + Ss 17408 + Ps 9216 + stats 768 = 158976 B.
__global__ __launch_bounds__(NTHREADS, 1)
void attn_v10(const float* __restrict__ A, const unsigned short* __restrict__ B16,
              float* __restrict__ Out) {
  __shared__ __align__(16) unsigned short Bs[BUFE];
  __shared__ __align__(16) unsigned short Qs[BUFE];
  __shared__ __align__(16) float Ss[QBLK * SROWP];
  __shared__ __align__(16) unsigned short Ps[QBLK * PROWP];
  __shared__ float mS[QBLK];
  __shared__ float lS[QBLK];
  __shared__ float aS[QBLK];

  const int tid  = threadIdx.x;
  const int wid  = tid >> 6;
  const int lane = tid & 63;
  const int l16  = lane & 15;
  const int g4   = lane >> 4;

  const int batch = blockIdx.x & 7;       // batch -> XCD (L2 locality for b panel)
  const int qt    = blockIdx.x >> 3;      // 0..31
  const int qbase = qt * QBLK;

  const float*          Ab   = A   + (size_t)batch * NSEQ * D;
  const unsigned short* Bb16 = B16 + (size_t)batch * NSEQ * D;
  float*                Ob   = Out + (size_t)batch * NSEQ * D;

  const float scale = 0.04419417382415922f;  // 1/sqrt(512)

  const int ki = wid & 3;    // wave's kv 16-tile for QK^T
  const int qp = wid >> 2;   // wave's q 32-half: tiles qp*2, qp*2+1

  // ---- stage Q into LDS (pre-scaled), subtiled layout ----
  // thread t: q = t>>3, d-chunk = (t&7)*64 .. +63  (8 x bf16x8 writes)
  {
    const int q  = tid >> 3;
    const int dc = (tid & 7) * 64;
    const float* src = Ab + (size_t)(qbase + q) * D + dc;
    const int gbase = (q >> 2) * ROWE + (q & 3) * 16;
    #pragma unroll
    for (int j = 0; j < 8; ++j) {
      float4 v0 = *reinterpret_cast<const float4*>(src + j * 8);
      float4 v1 = *reinterpret_cast<const float4*>(src + j * 8 + 4);
      bf16x8 h;
      h[0] = (short)f2b(v0.x * scale); h[1] = (short)f2b(v0.y * scale);
      h[2] = (short)f2b(v0.z * scale); h[3] = (short)f2b(v0.w * scale);
      h[4] = (short)f2b(v1.x * scale); h[5] = (short)f2b(v1.y * scale);
      h[6] = (short)f2b(v1.z * scale); h[7] = (short)f2b(v1.w * scale);
      int d = dc + j * 8;
      *reinterpret_cast<bf16x8*>(&Qs[gbase + (d >> 4) * 64 + (d & 15)]) = h;
    }
  }
  if (tid < QBLK) { mS[tid] = -1e30f; lS[tid] = 0.f; }

  f32x4 acc[4][4];
  #pragma unroll
  for (int mi = 0; mi < 4; ++mi)
    #pragma unroll
    for (int ni = 0; ni < 4; ++ni)
      acc[mi][ni] = (f32x4){0.f, 0.f, 0.f, 0.f};

  // ---- prologue: DMA tile 0 -> Bs ----
  #pragma unroll
  for (int c = 0; c < 8; ++c) {
    int id = wid * 8 + c;
    int g = id >> 2, q = id & 3;
    const unsigned short* src = Bb16
        + (size_t)(g * 4 + ((lane >> 1) & 3)) * D
        + q * 128 + (lane >> 3) * 16 + (lane & 1) * 8;
    unsigned short* dst = &Bs[g * ROWE + q * 512];
    __builtin_amdgcn_global_load_lds(
        (const __attribute__((address_space(1))) void*)src,
        (__attribute__((address_space(3))) void*)dst, 16, 0, 0);
  }
  asm volatile("s_waitcnt vmcnt(0)" ::: "memory");
  asm volatile("s_waitcnt lgkmcnt(0)" ::: "memory");
  __builtin_amdgcn_s_barrier();

  const int bbase = (ki * 4 + (l16 >> 2)) * ROWE + (l16 & 3) * 16 + (g4 & 1) * 8;
  const int qrb0  = ((qp * 2) * 4 + (l16 >> 2)) * ROWE + (l16 & 3) * 16 + (g4 & 1) * 8;
  const int qrb1  = qrb0 + 4 * ROWE;

  for (int kt = 0; kt < NT; ++kt) {
    // ---- QK^T: 2 S-tiles per wave (qp*2, qp*2+1) x ki; Q,B via b128 ----
    {
      f32x4 s0 = {0.f, 0.f, 0.f, 0.f};
      f32x4 s1 = {0.f, 0.f, 0.f, 0.f};
      __builtin_amdgcn_s_setprio(1);
      #pragma unroll
      for (int ks = 0; ks < 16; ++ks) {
        const int ro = (ks * 2 + (g4 >> 1)) * 64;
        const bf16x8 bf = *reinterpret_cast<const bf16x8*>(&Bs[bbase + ro]);
        const bf16x8 q0 = *reinterpret_cast<const bf16x8*>(&Qs[qrb0 + ro]);
        const bf16x8 q1 = *reinterpret_cast<const bf16x8*>(&Qs[qrb1 + ro]);
        s0 = __builtin_amdgcn_mfma_f32_16x16x32_bf16(q0, bf, s0, 0, 0, 0);
        s1 = __builtin_amdgcn_mfma_f32_16x16x32_bf16(q1, bf, s1, 0, 0, 0);
      }
      __builtin_amdgcn_s_setprio(0);
      #pragma unroll
      for (int r = 0; r < 4; ++r) {
        Ss[(qp * 32 + g4 * 4 + r) * SROWP + ki * 16 + l16]      = s0[r];
        Ss[(qp * 32 + 16 + g4 * 4 + r) * SROWP + ki * 16 + l16] = s1[r];
      }
    }
    asm volatile("s_waitcnt lgkmcnt(0)" ::: "memory");
    __builtin_amdgcn_s_barrier();

    // ---- online softmax: 8 lanes per row; lane owns 8-col chunk ----
    {
      int row = wid * 8 + (lane >> 3);
      int c8  = (lane & 7) * 8;
      float4 lo = *reinterpret_cast<const float4*>(&Ss[row * SROWP + c8]);
      float4 hi = *reinterpret_cast<const float4*>(&Ss[row * SROWP + c8 + 4]);
      float sv[8] = {lo.x, lo.y, lo.z, lo.w, hi.x, hi.y, hi.z, hi.w};
      float mloc = sv[0];
      #pragma unroll
      for (int j = 1; j < 8; ++j) mloc = fmaxf(mloc, sv[j]);
      #pragma unroll
      for (int off = 1; off < 8; off <<= 1)
        mloc = fmaxf(mloc, __shfl_xor(mloc, off));
      float mold = mS[row];
      float mnew = fmaxf(mold, mloc);
      float al = __expf(mold - mnew);
      float psum = 0.f;
      bf16x8 pw;
      #pragma unroll
      for (int j = 0; j < 8; ++j) {
        float p = __expf(sv[j] - mnew);
        psum += p;
        pw[j] = (short)f2b(p);
      }
      *reinterpret_cast<bf16x8*>(&Ps[row * PROWP + c8]) = pw;
      #pragma unroll
      for (int off = 1; off < 8; off <<= 1)
        psum += __shfl_xor(psum, off);
      if ((lane & 7) == 0) {
        mS[row] = mnew;
        lS[row] = lS[row] * al + psum;
        aS[row] = al;
      }
    }
    asm volatile("s_waitcnt lgkmcnt(0)" ::: "memory");
    __builtin_amdgcn_s_barrier();

    // ---- rescale acc + PV: wave owns d-slice [wid*64, +64) ----
    {
      #pragma unroll
      for (int mi = 0; mi < 4; ++mi)
        #pragma unroll
        for (int r = 0; r < 4; ++r) {
          float a = aS[mi * 16 + g4 * 4 + r];
          #pragma unroll
          for (int ni = 0; ni < 4; ++ni)
            acc[mi][ni][r] *= a;
        }

      const unsigned short* Bc = &Bs[0];
      __builtin_amdgcn_s_setprio(1);
      #pragma unroll
      for (int ks = 0; ks < 2; ++ks) {
        bf16x8 pf[4];
        #pragma unroll
        for (int mi = 0; mi < 4; ++mi)
          pf[mi] = *reinterpret_cast<const bf16x8*>(
              &Ps[(mi * 16 + l16) * PROWP + ks * 32 + g4 * 8]);
        #pragma unroll
        for (int ni = 0; ni < 4; ++ni) {
          bf16x8 vv;
          #pragma unroll
          for (int j = 0; j < 8; ++j)
            vv[j] = (short)Bc[(ks * 8 + g4 * 2 + (j >> 2)) * ROWE
                              + (wid * 4 + ni) * 64 + (j & 3) * 16 + l16];
          #pragma unroll
          for (int mi = 0; mi < 4; ++mi)
            acc[mi][ni] = __builtin_amdgcn_mfma_f32_16x16x32_bf16(pf[mi], vv, acc[mi][ni], 0, 0, 0);
        }
      }
      __builtin_amdgcn_s_setprio(0);
    }

    // ---- all PV reads of Bs done across the block -> safe to overwrite ----
    __builtin_amdgcn_s_barrier();
    if (kt + 1 < NT) {
      const unsigned short* Bt = Bb16 + (size_t)(kt + 1) * KVBLK * D;
      #pragma unroll
      for (int c = 0; c < 8; ++c) {
        int id = wid * 8 + c;
        int g = id >> 2, q = id & 3;
        const unsigned short* src = Bt
            + (size_t)(g * 4 + ((lane >> 1) & 3)) * D
            + q * 128 + (lane >> 3) * 16 + (lane & 1) * 8;
        unsigned short* dst = &Bs[g * ROWE + q * 512];
        __builtin_amdgcn_global_load_lds(
            (const __attribute__((address_space(1))) void*)src,
            (__attribute__((address_space(3))) void*)dst, 16, 0, 0);
      }
      asm volatile("s_waitcnt vmcnt(0)" ::: "memory");
    }
    __builtin_amdgcn_s_barrier();     // Bs(kt+1) ready for all waves
  }

  // ---- epilogue: out = acc / l + a ----
  #pragma unroll
  for (int mi = 0; mi < 4; ++mi)
    #pragma unroll
    for (int r = 0; r < 4; ++r) {
      float rl = 1.0f / lS[mi * 16 + g4 * 4 + r];
      #pragma unroll
      for (int ni = 0; ni < 4; ++ni) {
        int q = qbase + mi * 16 + g4 * 4 + r;
        int d = wid * 64 + ni * 16 + l16;
        size_t off = (size_t)q * D + d;
        Ob[off] = acc[mi][ni][r] * rl + Ab[off];
      }
    }
}

// ---------- fallback: in-kernel convert staging (no workspace) --------------
#define FQBLK 32
#define FSROWP (64 + 4)
#define FPROWP (64 + 8)
__global__ __launch_bounds__(NTHREADS, 2)
void attn_fb(const float* __restrict__ A, const float* __restrict__ B32,
             float* __restrict__ Out) {
  __shared__ __align__(16) unsigned short Bs[BUFE];
  __shared__ float Ss[FQBLK * FSROWP];
  __shared__ unsigned short Ps[FQBLK * FPROWP];
  __shared__ float mS[FQBLK];
  __shared__ float lS[FQBLK];
  __shared__ float aS[FQBLK];

  const int tid  = threadIdx.x;
  const int wid  = tid >> 6;
  const int lane = tid & 63;
  const int l16  = lane & 15;
  const int g4   = lane >> 4;

  const int batch = blockIdx.x & 7;
  const int qt    = blockIdx.x >> 3;
  const int qbase = qt * FQBLK;

  const float* Ab   = A   + (size_t)batch * NSEQ * D;
  const float* Bb32 = B32 + (size_t)batch * NSEQ * D;
  float*       Ob   = Out + (size_t)batch * NSEQ * D;

  const float scale = 0.04419417382415922f;

  const int qi = wid >> 2;
  const int ki = wid & 3;

  const float* Arow = Ab + (size_t)(qbase + qi * 16 + l16) * D;
  bf16x8 qf[16];
  #pragma unroll
  for (int ks = 0; ks < 16; ++ks) {
    int d0 = ks * 32 + g4 * 8;
    float4 v0 = *reinterpret_cast<const float4*>(Arow + d0);
    float4 v1 = *reinterpret_cast<const float4*>(Arow + d0 + 4);
    bf16x8 f;
    f[0] = (short)f2b(v0.x * scale); f[1] = (short)f2b(v0.y * scale);
    f[2] = (short)f2b(v0.z * scale); f[3] = (short)f2b(v0.w * scale);
    f[4] = (short)f2b(v1.x * scale); f[5] = (short)f2b(v1.y * scale);
    f[6] = (short)f2b(v1.z * scale); f[7] = (short)f2b(v1.w * scale);
    qf[ks] = f;
  }
  if (tid < FQBLK) { mS[tid] = -1e30f; lS[tid] = 0.f; }

  f32x4 acc[2][4];
  #pragma unroll
  for (int mi = 0; mi < 2; ++mi)
    #pragma unroll
    for (int ni = 0; ni < 4; ++ni)
      acc[mi][ni] = (f32x4){0.f, 0.f, 0.f, 0.f};

  for (int kt = 0; kt < NT; ++kt) {
    __builtin_amdgcn_s_barrier();
    const float* Bt = Bb32 + (size_t)kt * KVBLK * D;
    #pragma unroll
    for (int c = 0; c < 8; ++c) {
      int id = wid * 8 + c;
      int g = id >> 2, q = id & 3;
      int kv = g * 4 + ((lane >> 1) & 3);
      int d  = q * 128 + (lane >> 3) * 16 + (lane & 1) * 8;
      const float* s = Bt + (size_t)kv * D + d;
      float4 v0 = *reinterpret_cast<const float4*>(s);
      float4 v1 = *reinterpret_cast<const float4*>(s + 4);
      bf16x8 h;
      h[0] = (short)f2b(v0.x); h[1] = (short)f2b(v0.y);
      h[2] = (short)f2b(v0.z); h[3] = (short)f2b(v0.w);
      h[4] = (short)f2b(v1.x); h[5] = (short)f2b(v1.y);
      h[6] = (short)f2b(v1.z); h[7] = (short)f2b(v1.w);
      *reinterpret_cast<bf16x8*>(&Bs[g * ROWE + q * 512 + lane * 8]) = h;
    }
    asm volatile("s_waitcnt lgkmcnt(0)" ::: "memory");
    __builtin_amdgcn_s_barrier();

    {
      f32x4 s = {0.f, 0.f, 0.f, 0.f};
      const int bbase = (ki * 4 + (l16 >> 2)) * ROWE + (l16 & 3) * 16 + (g4 & 1) * 8;
      #pragma unroll
      for (int ks = 0; ks < 16; ++ks) {
        const bf16x8 bf = *reinterpret_cast<const bf16x8*>(
            &Bs[bbase + (ks * 2 + (g4 >> 1)) * 64]);
        s = __builtin_amdgcn_mfma_f32_16x16x32_bf16(qf[ks], bf, s, 0, 0, 0);
      }
      #pragma unroll
      for (int r = 0; r < 4; ++r)
        Ss[(qi * 16 + g4 * 4 + r) * FSROWP + ki * 16 + l16] = s[r];
    }
    asm volatile("s_waitcnt lgkmcnt(0)" ::: "memory");
    __builtin_amdgcn_s_barrier();

    {
      int row = wid * 4 + g4;
      float sv[4];
      float mloc = -1e30f;
      #pragma unroll
      for (int j = 0; j < 4; ++j) {
        sv[j] = Ss[row * FSROWP + l16 + 16 * j];
        mloc = fmaxf(mloc, sv[j]);
      }
      #pragma unroll
      for (int off = 1; off < 16; off <<= 1)
        mloc = fmaxf(mloc, __shfl_xor(mloc, off));
      float mold = mS[row];
      float mnew = fmaxf(mold, mloc);
      float al = __expf(mold - mnew);
      float psum = 0.f;
      #pragma unroll
      for (int j = 0; j < 4; ++j) {
        float p = __expf(sv[j] - mnew);
        psum += p;
        Ps[row * FPROWP + l16 + 16 * j] = f2b(p);
      }
      #pragma unroll
      for (int off = 1; off < 16; off <<= 1)
        psum += __shfl_xor(psum, off);
      if (l16 == 0) {
        mS[row] = mnew;
        lS[row] = lS[row] * al + psum;
        aS[row] = al;
      }
    }
    asm volatile("s_waitcnt lgkmcnt(0)" ::: "memory");
    __builtin_amdgcn_s_barrier();

    {
      #pragma unroll
      for (int mi = 0; mi < 2; ++mi)
        #pragma unroll
        for (int r = 0; r < 4; ++r) {
          float a = aS[mi * 16 + g4 * 4 + r];
          #pragma unroll
          for (int ni = 0; ni < 4; ++ni)
            acc[mi][ni][r] *= a;
        }

      #pragma unroll
      for (int ks = 0; ks < 2; ++ks) {
        bf16x8 pf[2];
        #pragma unroll
        for (int mi = 0; mi < 2; ++mi)
          pf[mi] = *reinterpret_cast<const bf16x8*>(
              &Ps[(mi * 16 + l16) * FPROWP + ks * 32 + g4 * 8]);
        #pragma unroll
        for (int ni = 0; ni < 4; ++ni) {
          bf16x8 vv;
          #pragma unroll
          for (int j = 0; j < 8; ++j)
            vv[j] = (short)Bs[(ks * 8 + g4 * 2 + (j >> 2)) * ROWE
                              + (wid * 4 + ni) * 64 + (j & 3) * 16 + l16];
          #pragma unroll
          for (int mi = 0; mi < 2; ++mi)
            acc[mi][ni] = __builtin_amdgcn_mfma_f32_16x16x32_bf16(pf[mi], vv, acc[mi][ni], 0, 0, 0);
        }
      }
    }
  }

  #pragma unroll
  for (int mi = 0; mi < 2; ++mi)
    #pragma unroll
    for (int r = 0; r < 4; ++r) {
      float rl = 1.0f / lS[mi * 16 + g4 * 4 + r];
      #pragma unroll
      for (int ni = 0; ni < 4; ++ni) {
        int q = qbase + mi * 16 + g4 * 4 + r;
        int d = wid * 64 + ni * 16 + l16;
        size_t off = (size_t)q * D + d;
        Ob[off] = acc[mi][ni][r] * rl + Ab[off];
      }
    }
}

extern "C" void kernel_launch(void* const* d_in, const int* in_sizes, int n_in,
                              void* d_out, int out_size, void* d_ws, size_t ws_size,
                              hipStream_t stream) {
  const float* a = (const float*)d_in[0];
  const float* b = (const float*)d_in[1];
  float* out = (float*)d_out;
  const size_t need = (size_t)NB * NSEQ * D * sizeof(unsigned short);  // 16 MB
  dim3 block(NTHREADS);
  if (ws_size >= need) {
    unsigned short* b16 = (unsigned short*)d_ws;
    conv_b16<<<4096, 256, 0, stream>>>(b, b16);
    dim3 grid(NB * (NSEQ / QBLK));            // 256 blocks = 1 per CU
    attn_v10<<<grid, block, 0, stream>>>(a, b16, out);
  } else {
    dim3 grid(NB * (NSEQ / FQBLK));
    attn_fb<<<grid, block, 0, stream>>>(a, b, out);
  }
}